// Round 8
// baseline (305.588 us; speedup 1.0000x reference)
//
#include <hip/hip_runtime.h>
#include <stdint.h>

#define M_DIM 8192
#define N_DIM 4096
#define K_DIM 4096
#define CBN   (K_DIM/8)   // 512 column groups per row

typedef __attribute__((ext_vector_type(8)))  short bf16x8;
typedef __attribute__((ext_vector_type(8)))  unsigned short u16x8;
typedef __attribute__((ext_vector_type(4)))  float f32x4;
typedef __attribute__((ext_vector_type(16))) float f32x16;

#define AS_GLOBAL(p) (const __attribute__((address_space(1))) void*)(p)
#define AS_LDS(p)    (__attribute__((address_space(3))) void*)(p)

static __device__ __forceinline__ unsigned short f2bf(float f) {
    union { float f; uint32_t u; } c; c.f = f;
    uint32_t u = c.u;
    return (unsigned short)((u + 0x7fffu + ((u >> 16) & 1u)) >> 16);
}

// ---------------------------------------------------------------------------
// Kernel 1: per (ob, cb) pick top-4 columns (of 8) by L1 mass over 64 rows.
// ---------------------------------------------------------------------------
__global__ __launch_bounds__(256) void venom_sel(const float* __restrict__ W,
                                                 uint16_t* __restrict__ sel) {
    int t   = threadIdx.x;
    int ob  = blockIdx.x;
    int col = blockIdx.y * 256 + t;
    const float* p = W + (size_t)(ob * 64) * K_DIM + col;
    double s = 0.0;
    #pragma unroll 16
    for (int r = 0; r < 64; ++r) s += fabsf(p[(size_t)r * K_DIM]);

    int lane = t & 63;
    int base = lane & ~7;
    double sc[8];
    #pragma unroll
    for (int j = 0; j < 8; ++j) sc[j] = __shfl(s, base + j, 64);

    uint32_t packed = 0;
    #pragma unroll
    for (int c = 0; c < 8; ++c) {
        int rank = 0;
        #pragma unroll
        for (int j = 0; j < 8; ++j)
            rank += (sc[j] > sc[c]) || (sc[j] == sc[c] && j < c);
        if (rank < 4) packed |= (uint32_t)c << (4 * rank);
    }
    if ((lane & 7) == 0) {
        int cb = col >> 3;
        sel[ob * CBN + cb] = (uint16_t)packed;
    }
}

// ---------------------------------------------------------------------------
// Kernel 2: masked bf16 weight pack (top-2 of selected 4 by |w|).
// ---------------------------------------------------------------------------
__global__ __launch_bounds__(256) void venom_pack(const float* __restrict__ W,
                                                  const uint16_t* __restrict__ sel,
                                                  unsigned short* __restrict__ Wb) {
    int gid = blockIdx.x * 256 + threadIdx.x;
    int o  = gid >> 9;
    int cb = gid & (CBN - 1);
    uint32_t pk = sel[(o >> 6) * CBN + cb];
    const float* p = W + (size_t)o * K_DIM + cb * 8;
    float4 a = *(const float4*)p;
    float4 b = *(const float4*)(p + 4);
    float w[8] = {a.x, a.y, a.z, a.w, b.x, b.y, b.z, b.w};

    int   c[4]; float v[4];
    #pragma unroll
    for (int pz = 0; pz < 4; ++pz) {
        c[pz] = (pk >> (4 * pz)) & 7;
        v[pz] = fabsf(w[c[pz]]);
    }
    uint32_t keep = 0;
    #pragma unroll
    for (int pz = 0; pz < 4; ++pz) {
        int cnt = 0;
        #pragma unroll
        for (int q = 0; q < 4; ++q)
            cnt += (v[q] > v[pz]) || (v[q] == v[pz] && q < pz);
        if (cnt < 2) keep |= 1u << c[pz];
    }
    u16x8 out;
    #pragma unroll
    for (int j = 0; j < 8; ++j)
        out[j] = f2bf(((keep >> j) & 1) ? w[j] : 0.0f);
    *(u16x8*)(Wb + (size_t)gid * 8) = out;
}

// ---------------------------------------------------------------------------
// Kernel 3: x f32 -> bf16 (RNE).
// ---------------------------------------------------------------------------
__global__ __launch_bounds__(256) void xcvt(const float* __restrict__ X,
                                            unsigned short* __restrict__ Xb) {
    size_t gid = (size_t)blockIdx.x * 256 + threadIdx.x;
    const float4* p = (const float4*)X + gid * 2;
    float4 a = p[0], b = p[1];
    float w[8] = {a.x, a.y, a.z, a.w, b.x, b.y, b.z, b.w};
    u16x8 out;
    #pragma unroll
    for (int j = 0; j < 8; ++j) out[j] = f2bf(w[j]);
    *(u16x8*)(Xb + gid * 8) = out;
}

// ---------------------------------------------------------------------------
// Kernel 4: 256x256 bf16 GEMM. Round-7 super-phase schedule (best measured),
// MFMA switched 16x16x32 -> 32x32x16 (µbench 2382 vs 2075 TF; half the
// instructions, same LDS bytes). Per SP (one 32-K slice):
//   { 12 ds_read (ks16=0 group: bfr0+af0 | SB | ks16=1 group: bfr1+af1)
//     | stageA(s+2) | lgkm(6) | 8 MFMA ks0 | stageB(s+2) | lgkm(0)
//     | 8 MFMA ks1 | vmcnt(4) | s_barrier }
// Frag layout (32x32x16): A/B lane = row(col) l&31, k = (l>>5)*8+j;
// C/D col = lane&31, row = (reg&3)+8*(reg>>2)+4*(lane>>5)  [m74/m101].
// XOR swizzle phys-chunk = c ^ ((R>>1)&3): R bits 1-2 come only from l32>>1
// -> per quarter-wave 2 lanes/bank = free minimum (verified 0 conflicts).
// vmcnt ledger identical to round 7 (steady CKPT4, tail CKPT0 at SP126).
// ---------------------------------------------------------------------------
__global__ __launch_bounds__(512, 2) void gemm256(const unsigned short* __restrict__ A,
                                                  const unsigned short* __restrict__ B,
                                                  const float* __restrict__ bias,
                                                  float* __restrict__ C) {
    __shared__ __align__(16) unsigned char smem[131072]; // A:[0,64K) B:[64K,128K)

    int t    = threadIdx.x;
    int wid  = t >> 6;
    int lane = t & 63;
    int l32  = lane & 31;
    int hk   = lane >> 5;           // k-group within a 16-k slice
    int wm   = wid >> 2;            // wave row-half (128 rows)
    int wn   = wid & 3;             // wave col-quarter (64 cols)

    // XCD-aware bijective swizzle (512 blocks % 8 == 0)
    int bid = blockIdx.x;
    int swz = (bid & 7) * ((int)gridDim.x >> 3) + (bid >> 3);
    int bm  = swz >> 4;
    int bn  = swz & 15;

    // staging: thread t covers row r=t>>2 (and r+128), phys chunk t&3 holds
    // logical chunk (t&3)^((r>>1)&3) = (t&3)^((t>>3)&3)
    int gch = ((t & 3) ^ ((t >> 3) & 3)) * 8;
    const unsigned short* agbase = A + (size_t)(bm * 256 + (t >> 2)) * K_DIM + gch;
    const unsigned short* bgbase = B + (size_t)(bn * 256 + (t >> 2)) * K_DIM + gch;

    auto stageA2 = [&](int slice, int bufp) {
        const unsigned short* ga = agbase + slice * 32;
        char* la = (char*)smem + bufp * 32768 + (slice & 1) * 16384 + wid * 1024;
        __builtin_amdgcn_global_load_lds(AS_GLOBAL(ga), AS_LDS(la), 16, 0, 0);
        __builtin_amdgcn_global_load_lds(AS_GLOBAL(ga + (size_t)128 * K_DIM), AS_LDS(la + 8192), 16, 0, 0);
    };
    auto stageB2 = [&](int slice, int bufp) {
        const unsigned short* gb = bgbase + slice * 32;
        char* lb = (char*)smem + 65536 + bufp * 32768 + (slice & 1) * 16384 + wid * 1024;
        __builtin_amdgcn_global_load_lds(AS_GLOBAL(gb), AS_LDS(lb), 16, 0, 0);
        __builtin_amdgcn_global_load_lds(AS_GLOBAL(gb + (size_t)128 * K_DIM), AS_LDS(lb + 8192), 16, 0, 0);
    };

    // read-side: row R = base + l32; 8-elem chunk c -> phys c ^ ((R>>1)&3);
    // (R>>1)&3 == (l32>>1)&3 because all frag bases are multiples of 32.
    int g3    = (l32 >> 1) & 3;
    int koff0 = ((hk      ^ g3)) << 4;   // ks16 = 0 : logical chunks {0,1}
    int koff1 = (((2 + hk) ^ g3)) << 4;  // ks16 = 1 : logical chunks {2,3}
    const char* ardb = (const char*)smem + (wm * 128 + l32) * 64;
    const char* brdb = (const char*)smem + 65536 + (wn * 64 + l32) * 64;

    f32x16 acc[4][2] = {};
    bf16x8 af0[4], af1[4], bfr0[2], bfr1[2];

#define LGKM(N) { asm volatile("s_waitcnt lgkmcnt(" #N ")" ::: "memory");            \
                  __builtin_amdgcn_sched_barrier(0); }
#define CKPT4() { asm volatile("s_waitcnt vmcnt(4)" ::: "memory");                   \
                  __builtin_amdgcn_sched_barrier(0); }
#define CKPT0() { asm volatile("s_waitcnt vmcnt(0)" ::: "memory");                   \
                  __builtin_amdgcn_sched_barrier(0); }
#define BAR()   { __builtin_amdgcn_s_barrier(); __builtin_amdgcn_sched_barrier(0); }

    // SP body. P: resident buf. K: ks32 within buf. SS: slice staged (s+2).
    // DOSTAGE: 0 none. CK: 0 none, 4 vmcnt(4), 1 vmcnt(0).
#define SP(P, K, SS, DOSTAGE, CK)                                                    \
    {                                                                                \
        const char* abase = ardb + (P) * 32768 + (K) * 16384;                        \
        const char* bbase = brdb + (P) * 32768 + (K) * 16384;                        \
        bfr0[0] = *(const bf16x8*)(bbase + 0 * 2048 + koff0);                        \
        bfr0[1] = *(const bf16x8*)(bbase + 1 * 2048 + koff0);                        \
        _Pragma("unroll")                                                            \
        for (int f = 0; f < 4; ++f)                                                  \
            af0[f] = *(const bf16x8*)(abase + f * 2048 + koff0);                     \
        __builtin_amdgcn_sched_barrier(0);                                           \
        bfr1[0] = *(const bf16x8*)(bbase + 0 * 2048 + koff1);                        \
        bfr1[1] = *(const bf16x8*)(bbase + 1 * 2048 + koff1);                        \
        _Pragma("unroll")                                                            \
        for (int f = 0; f < 4; ++f)                                                  \
            af1[f] = *(const bf16x8*)(abase + f * 2048 + koff1);                     \
        if (DOSTAGE) stageA2((SS), (P) ^ 1);                                         \
        LGKM(6)                                                                      \
        __builtin_amdgcn_s_setprio(1);                                               \
        _Pragma("unroll")                                                            \
        for (int f = 0; f < 4; ++f)                                                  \
            _Pragma("unroll")                                                        \
            for (int g = 0; g < 2; ++g)                                              \
                acc[f][g] = __builtin_amdgcn_mfma_f32_32x32x16_bf16(af0[f], bfr0[g], acc[f][g], 0, 0, 0); \
        __builtin_amdgcn_s_setprio(0);                                               \
        __builtin_amdgcn_sched_barrier(0);                                           \
        if (DOSTAGE) stageB2((SS), (P) ^ 1);                                         \
        LGKM(0)                                                                      \
        __builtin_amdgcn_s_setprio(1);                                               \
        _Pragma("unroll")                                                            \
        for (int f = 0; f < 4; ++f)                                                  \
            _Pragma("unroll")                                                        \
            for (int g = 0; g < 2; ++g)                                              \
                acc[f][g] = __builtin_amdgcn_mfma_f32_32x32x16_bf16(af1[f], bfr1[g], acc[f][g], 0, 0, 0); \
        __builtin_amdgcn_s_setprio(0);                                               \
        __builtin_amdgcn_sched_barrier(0);                                           \
        if ((CK) == 4) { CKPT4() } else if ((CK) == 1) { CKPT0() }                   \
        BAR()                                                                        \
    }

    // prologue: slices 0,1 -> buf0; drain slice0's 4 loads; sync
    stageA2(0, 0); stageB2(0, 0);
    stageA2(1, 0); stageB2(1, 0);
    CKPT4()
    BAR()

    for (int it = 0; it < 63; ++it) {
        int p = it & 1;
        SP(p, 0, 2 * (it + 1) + 0, 1, 4)   // slice 2it,   stage 2it+2
        SP(p, 1, 2 * (it + 1) + 1, 1, 4)   // slice 2it+1, stage 2it+3
    }
    // it = 63 (p = 1): slices 126, 127 — no stages
    SP(1, 0, 0, 0, 1)                      // vmcnt(0): drain stage@125 for 127
    SP(1, 1, 0, 0, 0)

    // epilogue: C/D 32x32 layout col = lane&31, row = (reg&3)+8*(reg>>2)+4*hk
    int    colb = bn * 256 + wn * 64;
    size_t rowb = (size_t)bm * 256 + wm * 128 + hk * 4;
    #pragma unroll
    for (int g = 0; g < 2; ++g) {
        int col = colb + g * 32 + l32;
        float bv = bias[col];
        #pragma unroll
        for (int f = 0; f < 4; ++f) {
            size_t r0 = rowb + f * 32;
            #pragma unroll
            for (int rg = 0; rg < 16; ++rg) {
                size_t row = r0 + (rg & 3) + 8 * (rg >> 2);
                C[row * N_DIM + col] = acc[f][g][rg] + bv;
            }
        }
    }
}

extern "C" void kernel_launch(void* const* d_in, const int* in_sizes, int n_in,
                              void* d_out, int out_size, void* d_ws, size_t ws_size,
                              hipStream_t stream) {
    const float* x    = (const float*)d_in[0];
    const float* W    = (const float*)d_in[1];
    const float* bias = (const float*)d_in[2];
    float* out = (float*)d_out;

    char* ws = (char*)d_ws;
    unsigned short* xb  = (unsigned short*)ws;                                   // 64 MB
    unsigned short* wb  = (unsigned short*)(ws + (size_t)M_DIM * K_DIM * 2);     // 32 MB
    uint16_t*       sel = (uint16_t*)(ws + (size_t)M_DIM * K_DIM * 2
                                         + (size_t)N_DIM * K_DIM * 2);           // 64 KB

    venom_sel <<<dim3(64, 16), 256, 0, stream>>>(W, sel);
    venom_pack<<<dim3((N_DIM * CBN) / 256), 256, 0, stream>>>(W, sel, wb);
    xcvt      <<<dim3((M_DIM * K_DIM / 8) / 256), 256, 0, stream>>>(x, xb);
    gemm256   <<<dim3((M_DIM / 256) * (N_DIM / 256)), 512, 0, stream>>>(xb, wb, bias, out);
}

// Round 9
// 282.989 us; speedup vs baseline: 1.0799x; 1.0799x over previous
//
#include <hip/hip_runtime.h>
#include <stdint.h>

#define M_DIM 8192
#define N_DIM 4096
#define K_DIM 4096
#define CBN   (K_DIM/8)   // 512 column groups per row

typedef __attribute__((ext_vector_type(8))) short bf16x8;
typedef __attribute__((ext_vector_type(8))) unsigned short u16x8;
typedef __attribute__((ext_vector_type(4))) float f32x4;

#define AS_GLOBAL(p) (const __attribute__((address_space(1))) void*)(p)
#define AS_LDS(p)    (__attribute__((address_space(3))) void*)(p)

static __device__ __forceinline__ unsigned short f2bf(float f) {
    union { float f; uint32_t u; } c; c.f = f;
    uint32_t u = c.u;
    return (unsigned short)((u + 0x7fffu + ((u >> 16) & 1u)) >> 16);
}

// ---------------------------------------------------------------------------
// Kernel 1: per (ob, cb) pick top-4 columns (of 8) by L1 mass over 64 rows.
// ---------------------------------------------------------------------------
__global__ __launch_bounds__(256) void venom_sel(const float* __restrict__ W,
                                                 uint16_t* __restrict__ sel) {
    int t   = threadIdx.x;
    int ob  = blockIdx.x;
    int col = blockIdx.y * 256 + t;
    const float* p = W + (size_t)(ob * 64) * K_DIM + col;
    double s = 0.0;
    #pragma unroll 16
    for (int r = 0; r < 64; ++r) s += fabsf(p[(size_t)r * K_DIM]);

    int lane = t & 63;
    int base = lane & ~7;
    double sc[8];
    #pragma unroll
    for (int j = 0; j < 8; ++j) sc[j] = __shfl(s, base + j, 64);

    uint32_t packed = 0;
    #pragma unroll
    for (int c = 0; c < 8; ++c) {
        int rank = 0;
        #pragma unroll
        for (int j = 0; j < 8; ++j)
            rank += (sc[j] > sc[c]) || (sc[j] == sc[c] && j < c);
        if (rank < 4) packed |= (uint32_t)c << (4 * rank);
    }
    if ((lane & 7) == 0) {
        int cb = col >> 3;
        sel[ob * CBN + cb] = (uint16_t)packed;
    }
}

// ---------------------------------------------------------------------------
// Kernel 2: masked bf16 weight pack (top-2 of selected 4 by |w|).
// ---------------------------------------------------------------------------
__global__ __launch_bounds__(256) void venom_pack(const float* __restrict__ W,
                                                  const uint16_t* __restrict__ sel,
                                                  unsigned short* __restrict__ Wb) {
    int gid = blockIdx.x * 256 + threadIdx.x;
    int o  = gid >> 9;
    int cb = gid & (CBN - 1);
    uint32_t pk = sel[(o >> 6) * CBN + cb];
    const float* p = W + (size_t)o * K_DIM + cb * 8;
    float4 a = *(const float4*)p;
    float4 b = *(const float4*)(p + 4);
    float w[8] = {a.x, a.y, a.z, a.w, b.x, b.y, b.z, b.w};

    int   c[4]; float v[4];
    #pragma unroll
    for (int pz = 0; pz < 4; ++pz) {
        c[pz] = (pk >> (4 * pz)) & 7;
        v[pz] = fabsf(w[c[pz]]);
    }
    uint32_t keep = 0;
    #pragma unroll
    for (int pz = 0; pz < 4; ++pz) {
        int cnt = 0;
        #pragma unroll
        for (int q = 0; q < 4; ++q)
            cnt += (v[q] > v[pz]) || (v[q] == v[pz] && q < pz);
        if (cnt < 2) keep |= 1u << c[pz];
    }
    u16x8 out;
    #pragma unroll
    for (int j = 0; j < 8; ++j)
        out[j] = f2bf(((keep >> j) & 1) ? w[j] : 0.0f);
    *(u16x8*)(Wb + (size_t)gid * 8) = out;
}

// ---------------------------------------------------------------------------
// Kernel 3: x f32 -> bf16 (RNE).
// ---------------------------------------------------------------------------
__global__ __launch_bounds__(256) void xcvt(const float* __restrict__ X,
                                            unsigned short* __restrict__ Xb) {
    size_t gid = (size_t)blockIdx.x * 256 + threadIdx.x;
    const float4* p = (const float4*)X + gid * 2;
    float4 a = p[0], b = p[1];
    float w[8] = {a.x, a.y, a.z, a.w, b.x, b.y, b.z, b.w};
    u16x8 out;
    #pragma unroll
    for (int j = 0; j < 8; ++j) out[j] = f2bf(w[j]);
    *(u16x8*)(Xb + gid * 8) = out;
}

// ---------------------------------------------------------------------------
// Kernel 4: 256x256 bf16 GEMM, tail-read pipeline. One SP per 32-K slice,
// ONE barrier per SP. Regions cycle mod 4 (16KB A + 16KB B each).
//   SP s: { lgkm(0) [reads from SP s-1 landed] | 32 MFMA (slice s regs)
//           | reads slice s+1 from R(s+1) | stage slice s+3 -> R(s+3)
//           | vmcnt(4) | s_barrier }
// Reads issue AFTER the MFMA cluster (sched_barrier-pinned): the post-barrier
// 96-read flood that serialized LDS service with MFMA (rounds 3-7, ~50%
// MfmaUtil) is gone; reads service under the barrier wait + MFMA tails.
// Ledger: R-after-W: reads@s of R(s+1) <- staged @s-2, drained CKPT@s-1
//   (outstanding = stage(s+1)@s-2 [oldest] + stage(s+2)@s-1 = 8, vmcnt(4))
//   + BAR@s-1 for cross-wave visibility. W-after-R: stage@s overwrites
//   R(s-1); its readers (slice s-1 @SP s-2) drained at their lgkm(0) top of
//   SP s-1, before BAR@s-1, before stage@s. Prologue: stage 0,1,2; vmcnt(4)
//   drains {0,1}; BAR; read slice 0. Tail: CKPT4@124 drains 126 (read @125),
//   CKPT0@125 drains 127 (read @126), none @126; SP127 = MFMA only.
// Frags: 16x16x32 (round-7 layout, 0 conflicts). XOR swizzle chunk^=(row>>1)&3
// on global source + read side. XCD-aware block swizzle.
// ---------------------------------------------------------------------------
__global__ __launch_bounds__(512, 2) void gemm256(const unsigned short* __restrict__ A,
                                                  const unsigned short* __restrict__ B,
                                                  const float* __restrict__ bias,
                                                  float* __restrict__ C) {
    __shared__ __align__(16) unsigned char smem[131072]; // A:[0,64K) B:[64K,128K)

    int t    = threadIdx.x;
    int wid  = t >> 6;
    int lane = t & 63;
    int l16  = lane & 15;
    int lk   = lane >> 4;
    int wm   = wid >> 2;     // wave row-half (128 rows)
    int wn   = wid & 3;      // wave col-quarter (64 cols)

    // XCD-aware bijective swizzle (512 blocks % 8 == 0)
    int bid = blockIdx.x;
    int swz = (bid & 7) * ((int)gridDim.x >> 3) + (bid >> 3);
    int bm  = swz >> 4;
    int bn  = swz & 15;

    // staging: thread t covers row r=t>>2 (and r+128), phys chunk t&3 holds
    // logical chunk (t&3)^((r>>1)&3) = (t&3)^((t>>3)&3)
    int gch = ((t & 3) ^ ((t >> 3) & 3)) * 8;
    const unsigned short* agbase = A + (size_t)(bm * 256 + (t >> 2)) * K_DIM + gch;
    const unsigned short* bgbase = B + (size_t)(bn * 256 + (t >> 2)) * K_DIM + gch;

    auto stageA2 = [&](int slice) {
        const unsigned short* ga = agbase + slice * 32;
        char* la = (char*)smem + (slice & 3) * 16384 + wid * 1024;
        __builtin_amdgcn_global_load_lds(AS_GLOBAL(ga), AS_LDS(la), 16, 0, 0);
        __builtin_amdgcn_global_load_lds(AS_GLOBAL(ga + (size_t)128 * K_DIM), AS_LDS(la + 8192), 16, 0, 0);
    };
    auto stageB2 = [&](int slice) {
        const unsigned short* gb = bgbase + slice * 32;
        char* lb = (char*)smem + 65536 + (slice & 3) * 16384 + wid * 1024;
        __builtin_amdgcn_global_load_lds(AS_GLOBAL(gb), AS_LDS(lb), 16, 0, 0);
        __builtin_amdgcn_global_load_lds(AS_GLOBAL(gb + (size_t)128 * K_DIM), AS_LDS(lb + 8192), 16, 0, 0);
    };

    // read-side: row R = base+l16, k-chunk lk -> phys chunk lk^((l16>>1)&3)
    int koff = ((lk ^ ((l16 >> 1) & 3)) << 4);
    const char* ardb = (const char*)smem + (wm * 128 + l16) * 64 + koff;
    const char* brdb = (const char*)smem + 65536 + (wn * 64 + l16) * 64 + koff;

    f32x4 acc[8][4] = {};
    bf16x8 af0[4], af1[4], bfr[4];

#define LGKM0() { asm volatile("s_waitcnt lgkmcnt(0)" ::: "memory");                 \
                  __builtin_amdgcn_sched_barrier(0); }
#define CKPT4() { asm volatile("s_waitcnt vmcnt(4)" ::: "memory");                   \
                  __builtin_amdgcn_sched_barrier(0); }
#define CKPT0() { asm volatile("s_waitcnt vmcnt(0)" ::: "memory");                   \
                  __builtin_amdgcn_sched_barrier(0); }
#define BAR()   { __builtin_amdgcn_s_barrier(); __builtin_amdgcn_sched_barrier(0); }

#define RDNXT(RN)                                                                    \
    {                                                                                \
        _Pragma("unroll")                                                            \
        for (int g = 0; g < 4; ++g)                                                  \
            bfr[g] = *(const bf16x8*)(brdb + (RN) * 16384 + g * 1024);               \
        _Pragma("unroll")                                                            \
        for (int i = 0; i < 4; ++i)                                                  \
            af0[i] = *(const bf16x8*)(ardb + (RN) * 16384 + i * 1024);               \
        _Pragma("unroll")                                                            \
        for (int i = 0; i < 4; ++i)                                                  \
            af1[i] = *(const bf16x8*)(ardb + (RN) * 16384 + 4096 + i * 1024);        \
    }

#define MFMA32()                                                                     \
    {                                                                                \
        __builtin_amdgcn_s_setprio(1);                                               \
        _Pragma("unroll")                                                            \
        for (int i = 0; i < 4; ++i)                                                  \
            _Pragma("unroll")                                                        \
            for (int g = 0; g < 4; ++g)                                              \
                acc[i][g] = __builtin_amdgcn_mfma_f32_16x16x32_bf16(af0[i], bfr[g], acc[i][g], 0, 0, 0); \
        _Pragma("unroll")                                                            \
        for (int i = 0; i < 4; ++i)                                                  \
            _Pragma("unroll")                                                        \
            for (int g = 0; g < 4; ++g)                                              \
                acc[4+i][g] = __builtin_amdgcn_mfma_f32_16x16x32_bf16(af1[i], bfr[g], acc[4+i][g], 0, 0, 0); \
        __builtin_amdgcn_s_setprio(0);                                               \
        __builtin_amdgcn_sched_barrier(0);                                           \
    }

    // SP: RN = region of slice s+1; DOSTAGE + SS = slice s+3; CK: 4/1/0
#define SP(RN, DOSTAGE, SS, CK)                                                      \
    {                                                                                \
        LGKM0()                                                                      \
        MFMA32()                                                                     \
        RDNXT(RN)                                                                    \
        if (DOSTAGE) { stageA2(SS); stageB2(SS); }                                   \
        if ((CK) == 4) { CKPT4() } else if ((CK) == 1) { CKPT0() }                   \
        BAR()                                                                        \
    }

    // prologue: stage slices 0,1,2; drain 0,1 (12 outstanding -> vmcnt(4));
    // barrier; pre-read slice 0 into regs.
    stageA2(0); stageB2(0);
    stageA2(1); stageB2(1);
    stageA2(2); stageB2(2);
    CKPT4()
    BAR()
    RDNXT(0)

    // slices 0..123 uniform (region of s+1 cycles 1,2,3,0; stage s+3 <= 126)
    for (int s4 = 0; s4 < 31; ++s4) {
        int s = s4 * 4;
        SP(1, 1, s + 3, 4)
        SP(2, 1, s + 4, 4)
        SP(3, 1, s + 5, 4)
        SP(0, 1, s + 6, 4)
    }
    // tail: s = 124..127
    SP(1, 1, 127, 4)      // s=124: stage 127; CKPT4 drains 126 (read @125)
    SP(2, 0, 0,   1)      // s=125: CKPT0 drains 127 (read @126)
    SP(3, 0, 0,   0)      // s=126: reads slice 127; nothing outstanding
    LGKM0()               // s=127: MFMA only
    MFMA32()

    // epilogue: C/D layout col = lane&15, row = (lane>>4)*4 + reg
    int    colb = bn * 256 + wn * 64;
    size_t rowb = (size_t)bm * 256 + wm * 128 + (lk << 2);
    #pragma unroll
    for (int g = 0; g < 4; ++g) {
        int col = colb + g * 16 + l16;
        float bv = bias[col];
        #pragma unroll
        for (int f = 0; f < 8; ++f) {
            size_t r0 = rowb + f * 16;
            #pragma unroll
            for (int rg = 0; rg < 4; ++rg)
                C[(r0 + rg) * N_DIM + col] = acc[f][g][rg] + bv;
        }
    }
}

extern "C" void kernel_launch(void* const* d_in, const int* in_sizes, int n_in,
                              void* d_out, int out_size, void* d_ws, size_t ws_size,
                              hipStream_t stream) {
    const float* x    = (const float*)d_in[0];
    const float* W    = (const float*)d_in[1];
    const float* bias = (const float*)d_in[2];
    float* out = (float*)d_out;

    char* ws = (char*)d_ws;
    unsigned short* xb  = (unsigned short*)ws;                                   // 64 MB
    unsigned short* wb  = (unsigned short*)(ws + (size_t)M_DIM * K_DIM * 2);     // 32 MB
    uint16_t*       sel = (uint16_t*)(ws + (size_t)M_DIM * K_DIM * 2
                                         + (size_t)N_DIM * K_DIM * 2);           // 64 KB

    venom_sel <<<dim3(64, 16), 256, 0, stream>>>(W, sel);
    venom_pack<<<dim3((N_DIM * CBN) / 256), 256, 0, stream>>>(W, sel, wb);
    xcvt      <<<dim3((M_DIM * K_DIM / 8) / 256), 256, 0, stream>>>(x, xb);
    gemm256   <<<dim3((M_DIM / 256) * (N_DIM / 256)), 512, 0, stream>>>(xb, wb, bias, out);
}